// Round 9
// baseline (120.765 us; speedup 1.0000x reference)
//
#include <hip/hip_runtime.h>

#define D_MODEL 256
#define LN_EPS 1e-5f
#define NWAVES 8192
#define NITER  64            // 524288 rows / 8192 waves

typedef float f4 __attribute__((ext_vector_type(4)));

// Force a wave-uniform float into an SGPR.
__device__ __forceinline__ float rfl(float x) {
    return __uint_as_float(__builtin_amdgcn_readfirstlane(__float_as_uint(x)));
}

// ---------------------------------------------------------------------------
// R9: fill-style GRID-STRIDE write front. Wave w writes rows w + i*8192
// (i = 0..63), so all 8192 waves form one dense contiguous 8 MB moving front
// (like the 6.7 TB/s fill kernels) instead of 8192 scattered 1-KiB windows
// spaced 64 KiB apart (DRAM row-buffer thrash).
// Index algebra: 8192 = 2^13 -> SC = w&511 and fU = (w>>9)&3 are per-wave
// constants; only fB = ((w>>11) + 4i) & 63 varies. Fold fS,fU into per-lane
// w2(d); evaluate the 4x4 Gram quadratic form at (re, im, fB).
// CSI via uniform s_loads; NT stores (R7 A/B: NT beats plain by 10%).
// ---------------------------------------------------------------------------
__global__ __launch_bounds__(256, 8) void csi_encoder_kernel(
    const float* __restrict__ csi_real,
    const float* __restrict__ csi_imag,
    const float* __restrict__ w_c,
    const float* __restrict__ b_c,
    const float* __restrict__ w_s,
    const float* __restrict__ b_s,
    const float* __restrict__ w_u,
    const float* __restrict__ b_u,
    const float* __restrict__ w_f,
    const float* __restrict__ b_f,
    const float* __restrict__ ln_gamma,
    const float* __restrict__ ln_beta,
    float* __restrict__ out)
{
    const int lane = threadIdx.x & 63;
    const int waveId = blockIdx.x * 4 + (threadIdx.x >> 6);   // 0..8191
    const int w0 = __builtin_amdgcn_readfirstlane(waveId);

    const float fS = (float)(w0 & 511);          // per-wave constant
    const float fU = (float)((w0 >> 9) & 3);     // per-wave constant
    const int   b0 = (w0 >> 11) & 63;            // fB start; +4 per iter mod 64

    // Per-lane (per-d) constants for d = d0..d0+3.
    const int d0 = lane * 4;
    float a0[4], a1[4], aB[4], w2[4], gv[4], bv[4];
#pragma unroll
    for (int j = 0; j < 4; ++j) {
        const int d = d0 + j;
        a0[j] = w_c[d * 2 + 0];
        a1[j] = w_c[d * 2 + 1];
        aB[j] = w_s[d];
        const float bsum = b_c[d] + b_s[d] + b_u[d] + b_f[d];
        w2[j] = fmaf(fS, w_f[d], fmaf(fU, w_u[d], bsum));
        gv[j] = ln_gamma[d];
        bv[j] = ln_beta[d];
    }

    // 14 sums over d: 4x4 Gram (10) + means (4) of h = (a0, a1, aB, w2).
    float p[14];
#pragma unroll
    for (int i = 0; i < 14; ++i) p[i] = 0.0f;
#pragma unroll
    for (int j = 0; j < 4; ++j) {
        p[0]  = fmaf(a0[j], a0[j], p[0]);
        p[1]  = fmaf(a1[j], a1[j], p[1]);
        p[2]  = fmaf(aB[j], aB[j], p[2]);
        p[3]  = fmaf(w2[j], w2[j], p[3]);
        p[4]  = fmaf(a0[j], a1[j], p[4]);
        p[5]  = fmaf(a0[j], aB[j], p[5]);
        p[6]  = fmaf(a0[j], w2[j], p[6]);
        p[7]  = fmaf(a1[j], aB[j], p[7]);
        p[8]  = fmaf(a1[j], w2[j], p[8]);
        p[9]  = fmaf(aB[j], w2[j], p[9]);
        p[10] += a0[j];
        p[11] += a1[j];
        p[12] += aB[j];
        p[13] += w2[j];
    }
#pragma unroll
    for (int off = 32; off >= 1; off >>= 1) {
#pragma unroll
        for (int i = 0; i < 14; ++i) p[i] += __shfl_xor(p[i], off, 64);
    }

    // Wave-uniform Gram constants -> SGPRs.
    const float inv = 1.0f / 256.0f;
    const float E00 = rfl(p[0] * inv);
    const float E11 = rfl(p[1] * inv);
    const float EBB = rfl(p[2] * inv);
    const float E33 = rfl(p[3] * inv);
    const float F01 = rfl(2.0f * p[4] * inv);
    const float F0B = rfl(2.0f * p[5] * inv);
    const float F03 = rfl(2.0f * p[6] * inv);
    const float F1B = rfl(2.0f * p[7] * inv);
    const float F13 = rfl(2.0f * p[8] * inv);
    const float FB3 = rfl(2.0f * p[9] * inv);
    const float M0  = rfl(p[10] * inv);
    const float M1  = rfl(p[11] * inv);
    const float MB  = rfl(p[12] * inv);
    const float M3  = rfl(p[13] * inv);

    // Uniform base pointers; per-iteration strides: CSI 8192 floats (32 KB),
    // out 8192 rows (8 MB).
    const float* __restrict__ cr = csi_real + w0;
    const float* __restrict__ ci = csi_imag + w0;
    float* __restrict__ op = out + (size_t)w0 * D_MODEL + d0;

#pragma unroll 4
    for (int i = 0; i < NITER; ++i) {
        const float re = cr[(size_t)i << 13];    // uniform -> s_load
        const float im = ci[(size_t)i << 13];    // uniform -> s_load
        const float fB = (float)((b0 + 4 * i) & 63);

        const float mu = fmaf(M0, re, fmaf(M1, im, fmaf(MB, fB, M3)));
        const float ms = fmaf(re, fmaf(E00, re, fmaf(F01, im, fmaf(F0B, fB, F03))),
                         fmaf(im, fmaf(E11, im, fmaf(F1B, fB, F13)),
                         fmaf(fB, fmaf(EBB, fB, FB3), E33)));
        const float var  = fmaf(-mu, mu, ms);
        const float rstd = rsqrtf(var + LN_EPS);

        f4 o;
#pragma unroll
        for (int k = 0; k < 4; ++k) {
            const float t = fmaf(re, a0[k], fmaf(im, a1[k], fmaf(fB, aB[k], w2[k])));
            o[k] = fmaf((t - mu) * rstd, gv[k], bv[k]);
        }
        __builtin_nontemporal_store(o, (f4*)(op + ((size_t)i << 13) * D_MODEL));
    }
}

extern "C" void kernel_launch(void* const* d_in, const int* in_sizes, int n_in,
                              void* d_out, int out_size, void* d_ws, size_t ws_size,
                              hipStream_t stream) {
    const float* csi_real = (const float*)d_in[0];
    const float* csi_imag = (const float*)d_in[1];
    const float* w_c      = (const float*)d_in[2];
    const float* b_c      = (const float*)d_in[3];
    const float* w_s      = (const float*)d_in[4];
    const float* b_s      = (const float*)d_in[5];
    const float* w_u      = (const float*)d_in[6];
    const float* b_u      = (const float*)d_in[7];
    const float* w_f      = (const float*)d_in[8];
    const float* b_f      = (const float*)d_in[9];
    const float* ln_gamma = (const float*)d_in[10];
    const float* ln_beta  = (const float*)d_in[11];
    float* out = (float*)d_out;

    // 2048 blocks x 4 waves = 8192 waves, grid-striding 64 rows each.
    csi_encoder_kernel<<<2048, 256, 0, stream>>>(
        csi_real, csi_imag, w_c, b_c, w_s, b_s, w_u, b_u, w_f, b_f,
        ln_gamma, ln_beta, out);
}

// Round 10
// 114.421 us; speedup vs baseline: 1.0554x; 1.0554x over previous
//
#include <hip/hip_runtime.h>

#define D_MODEL 256
#define LN_EPS 1e-5f
#define NITER  256           // rows per wave: 524288 / 2048 waves

typedef float f4 __attribute__((ext_vector_type(4)));

// Force a wave-uniform float into an SGPR.
__device__ __forceinline__ float rfl(float x) {
    return __uint_as_float(__builtin_amdgcn_readfirstlane(__float_as_uint(x)));
}

// ---------------------------------------------------------------------------
// R10: LOW-STREAM-COUNT chunked variant. 512 blocks x 4 waves = 2048 waves,
// each owning 256 CONTIGUOUS rows (256 KiB). 8 waves/CU -> 8 write streams
// per CU with 4x longer sequential runs (fill kernels run at ~3.4 waves/CU
// and hit 6.7 TB/s; R8 showed 16 vs 32 waves/CU identical, so we probe the
// other direction). Everything else = R8: NT stores, s_load CSI path,
// SGPR Gram constants, closed-form LayerNorm.
// Index algebra: rbase = 256*w -> s0i in {0,256}, fS = s0i+j <= 511 stays
// within the subcarrier segment; fU/fB per-wave constants.
// ---------------------------------------------------------------------------
__global__ __launch_bounds__(256, 8) void csi_encoder_kernel(
    const float* __restrict__ csi_real,
    const float* __restrict__ csi_imag,
    const float* __restrict__ w_c,
    const float* __restrict__ b_c,
    const float* __restrict__ w_s,
    const float* __restrict__ b_s,
    const float* __restrict__ w_u,
    const float* __restrict__ b_u,
    const float* __restrict__ w_f,
    const float* __restrict__ b_f,
    const float* __restrict__ ln_gamma,
    const float* __restrict__ ln_beta,
    float* __restrict__ out)
{
    const int lane = threadIdx.x & 63;
    const int waveId = blockIdx.x * 4 + (threadIdx.x >> 6);   // 0..2047
    const int rbase = __builtin_amdgcn_readfirstlane(waveId * NITER);

    const int s0i = rbase & 511;                 // 0 or 256
    const float fU = (float)((rbase >> 9) & 3);
    const float fB = (float)((rbase >> 11) & 63);

    // Per-lane (per-d) constants for d = d0..d0+3.
    const int d0 = lane * 4;
    float a0[4], a1[4], a2[4], wv[4], gv[4], bv[4];
#pragma unroll
    for (int j = 0; j < 4; ++j) {
        const int d = d0 + j;
        a0[j] = w_c[d * 2 + 0];
        a1[j] = w_c[d * 2 + 1];
        a2[j] = w_f[d];
        const float bsum = b_c[d] + b_s[d] + b_u[d] + b_f[d];
        wv[j] = fmaf(fB, w_s[d], fmaf(fU, w_u[d], bsum));
        gv[j] = ln_gamma[d];
        bv[j] = ln_beta[d];
    }

    // 14 sums over d: 4x4 Gram (10) + means (4) of h = (a0, a1, a2, w).
    float p[14];
#pragma unroll
    for (int i = 0; i < 14; ++i) p[i] = 0.0f;
#pragma unroll
    for (int j = 0; j < 4; ++j) {
        p[0]  = fmaf(a0[j], a0[j], p[0]);
        p[1]  = fmaf(a1[j], a1[j], p[1]);
        p[2]  = fmaf(a2[j], a2[j], p[2]);
        p[3]  = fmaf(wv[j], wv[j], p[3]);
        p[4]  = fmaf(a0[j], a1[j], p[4]);
        p[5]  = fmaf(a0[j], a2[j], p[5]);
        p[6]  = fmaf(a0[j], wv[j], p[6]);
        p[7]  = fmaf(a1[j], a2[j], p[7]);
        p[8]  = fmaf(a1[j], wv[j], p[8]);
        p[9]  = fmaf(a2[j], wv[j], p[9]);
        p[10] += a0[j];
        p[11] += a1[j];
        p[12] += a2[j];
        p[13] += wv[j];
    }
#pragma unroll
    for (int off = 32; off >= 1; off >>= 1) {
#pragma unroll
        for (int i = 0; i < 14; ++i) p[i] += __shfl_xor(p[i], off, 64);
    }

    // Wave-uniform Gram constants -> SGPRs.
    const float inv = 1.0f / 256.0f;
    const float E00 = rfl(p[0] * inv);
    const float E11 = rfl(p[1] * inv);
    const float E22 = rfl(p[2] * inv);
    const float E33 = rfl(p[3] * inv);
    const float F01 = rfl(2.0f * p[4] * inv);
    const float F02 = rfl(2.0f * p[5] * inv);
    const float F03 = rfl(2.0f * p[6] * inv);
    const float F12 = rfl(2.0f * p[7] * inv);
    const float F13 = rfl(2.0f * p[8] * inv);
    const float F23 = rfl(2.0f * p[9] * inv);
    const float M0  = rfl(p[10] * inv);
    const float M1  = rfl(p[11] * inv);
    const float M2  = rfl(p[12] * inv);
    const float M3  = rfl(p[13] * inv);

    // Uniform base pointers for this wave's 256-row chunk.
    const float* __restrict__ cr = csi_real + rbase;
    const float* __restrict__ ci = csi_imag + rbase;
    float* __restrict__ op = out + (size_t)rbase * D_MODEL + d0;

#pragma unroll 4
    for (int j = 0; j < NITER; ++j) {
        const float re = cr[j];              // uniform -> s_load (lgkmcnt)
        const float im = ci[j];              // uniform -> s_load (lgkmcnt)
        const float fS = (float)(s0i + j);

        const float mu = fmaf(M0, re, fmaf(M1, im, fmaf(M2, fS, M3)));
        const float ms = fmaf(re, fmaf(E00, re, fmaf(F01, im, fmaf(F02, fS, F03))),
                         fmaf(im, fmaf(E11, im, fmaf(F12, fS, F13)),
                         fmaf(fS, fmaf(E22, fS, F23), E33)));
        const float var  = fmaf(-mu, mu, ms);
        const float rstd = rsqrtf(var + LN_EPS);

        f4 o;
#pragma unroll
        for (int k = 0; k < 4; ++k) {
            const float t = fmaf(re, a0[k], fmaf(im, a1[k], fmaf(fS, a2[k], wv[k])));
            o[k] = fmaf((t - mu) * rstd, gv[k], bv[k]);
        }
        __builtin_nontemporal_store(o, (f4*)(op + (size_t)j * D_MODEL));
    }
}

extern "C" void kernel_launch(void* const* d_in, const int* in_sizes, int n_in,
                              void* d_out, int out_size, void* d_ws, size_t ws_size,
                              hipStream_t stream) {
    const float* csi_real = (const float*)d_in[0];
    const float* csi_imag = (const float*)d_in[1];
    const float* w_c      = (const float*)d_in[2];
    const float* b_c      = (const float*)d_in[3];
    const float* w_s      = (const float*)d_in[4];
    const float* b_s      = (const float*)d_in[5];
    const float* w_u      = (const float*)d_in[6];
    const float* b_u      = (const float*)d_in[7];
    const float* w_f      = (const float*)d_in[8];
    const float* b_f      = (const float*)d_in[9];
    const float* ln_gamma = (const float*)d_in[10];
    const float* ln_beta  = (const float*)d_in[11];
    float* out = (float*)d_out;

    // 512 blocks x 4 waves = 2048 waves; each owns 256 contiguous rows.
    csi_encoder_kernel<<<512, 256, 0, stream>>>(
        csi_real, csi_imag, w_c, b_c, w_s, b_s, w_u, b_u, w_f, b_f,
        ln_gamma, ln_beta, out);
}

// Round 11
// 102.730 us; speedup vs baseline: 1.1756x; 1.1138x over previous
//
#include <hip/hip_runtime.h>

#define D_MODEL 256
#define LN_EPS 1e-5f

typedef float f4 __attribute__((ext_vector_type(4)));

// Force a wave-uniform float into an SGPR.
__device__ __forceinline__ float rfl(float x) {
    return __uint_as_float(__builtin_amdgcn_readfirstlane(__float_as_uint(x)));
}
// Broadcast lane j's value of v (wave-uniform j) — VALU op, no memory counter.
__device__ __forceinline__ float rdlane(float v, int j) {
    return __uint_as_float(__builtin_amdgcn_readlane(__float_as_uint(v), j));
}

// ---------------------------------------------------------------------------
// R11 = R8 (best: 8192 waves x 64-row contiguous chunks, NT stores, SGPR Gram
// constants, closed-form LayerNorm) + ZERO in-loop memory reads:
// the wave's whole 64-row CSI chunk is held in 2 VGPRs (lane l = row rbase+l),
// loaded once in the prologue (2 coalesced 256-B loads, hidden under the Gram
// butterfly). Rows are broadcast per-iteration via v_readlane — no s_loads,
// no lgkmcnt(0) drains in the loop. The 64-store loop contains only VALU +
// nontemporal stores; stores queue up to the vmcnt cap with no waits.
// Rationale: SMEM returns are unordered -> only full lgkmcnt(0) waits are
// possible -> s_loads can't be software-pipelined; fill kernels (6.7 TB/s on
// this buffer) have zero loads. This removes the last in-loop stall source.
// ---------------------------------------------------------------------------
__global__ __launch_bounds__(256, 8) void csi_encoder_kernel(
    const float* __restrict__ csi_real,
    const float* __restrict__ csi_imag,
    const float* __restrict__ w_c,
    const float* __restrict__ b_c,
    const float* __restrict__ w_s,
    const float* __restrict__ b_s,
    const float* __restrict__ w_u,
    const float* __restrict__ b_u,
    const float* __restrict__ w_f,
    const float* __restrict__ b_f,
    const float* __restrict__ ln_gamma,
    const float* __restrict__ ln_beta,
    float* __restrict__ out)
{
    const int lane = threadIdx.x & 63;
    const int waveId = blockIdx.x * 4 + (threadIdx.x >> 6);   // 0..8191
    const int rbase = __builtin_amdgcn_readfirstlane(waveId * 64);

    // Prologue CSI loads: lane l holds row (rbase+l). Issued first so their
    // latency hides under the coefficient loads + Gram butterfly below.
    const float re_v = csi_real[rbase + lane];
    const float im_v = csi_imag[rbase + lane];

    const int s0i = rbase & 511;                 // starting subcarrier index
    const float fU = (float)((rbase >> 9) & 3);
    const float fB = (float)((rbase >> 11) & 63);

    // Per-lane (per-d) constants for d = d0..d0+3.
    const int d0 = lane * 4;
    float a0[4], a1[4], a2[4], wv[4], gv[4], bv[4];
#pragma unroll
    for (int j = 0; j < 4; ++j) {
        const int d = d0 + j;
        a0[j] = w_c[d * 2 + 0];
        a1[j] = w_c[d * 2 + 1];
        a2[j] = w_f[d];
        const float bsum = b_c[d] + b_s[d] + b_u[d] + b_f[d];
        wv[j] = fmaf(fB, w_s[d], fmaf(fU, w_u[d], bsum));
        gv[j] = ln_gamma[d];
        bv[j] = ln_beta[d];
    }

    // 14 sums over d: 4x4 Gram (10) + means (4) of h = (a0, a1, a2, w).
    float p[14];
#pragma unroll
    for (int i = 0; i < 14; ++i) p[i] = 0.0f;
#pragma unroll
    for (int j = 0; j < 4; ++j) {
        p[0]  = fmaf(a0[j], a0[j], p[0]);
        p[1]  = fmaf(a1[j], a1[j], p[1]);
        p[2]  = fmaf(a2[j], a2[j], p[2]);
        p[3]  = fmaf(wv[j], wv[j], p[3]);
        p[4]  = fmaf(a0[j], a1[j], p[4]);
        p[5]  = fmaf(a0[j], a2[j], p[5]);
        p[6]  = fmaf(a0[j], wv[j], p[6]);
        p[7]  = fmaf(a1[j], a2[j], p[7]);
        p[8]  = fmaf(a1[j], wv[j], p[8]);
        p[9]  = fmaf(a2[j], wv[j], p[9]);
        p[10] += a0[j];
        p[11] += a1[j];
        p[12] += a2[j];
        p[13] += wv[j];
    }
#pragma unroll
    for (int off = 32; off >= 1; off >>= 1) {
#pragma unroll
        for (int i = 0; i < 14; ++i) p[i] += __shfl_xor(p[i], off, 64);
    }

    // Wave-uniform Gram constants -> SGPRs.
    const float inv = 1.0f / 256.0f;
    const float E00 = rfl(p[0] * inv);
    const float E11 = rfl(p[1] * inv);
    const float E22 = rfl(p[2] * inv);
    const float E33 = rfl(p[3] * inv);
    const float F01 = rfl(2.0f * p[4] * inv);
    const float F02 = rfl(2.0f * p[5] * inv);
    const float F03 = rfl(2.0f * p[6] * inv);
    const float F12 = rfl(2.0f * p[7] * inv);
    const float F13 = rfl(2.0f * p[8] * inv);
    const float F23 = rfl(2.0f * p[9] * inv);
    const float M0  = rfl(p[10] * inv);
    const float M1  = rfl(p[11] * inv);
    const float M2  = rfl(p[12] * inv);
    const float M3  = rfl(p[13] * inv);

    float* __restrict__ op = out + (size_t)rbase * D_MODEL + d0;

#pragma unroll 4
    for (int j = 0; j < 64; ++j) {
        const float re = rdlane(re_v, j);    // v_readlane: no memory counter
        const float im = rdlane(im_v, j);
        const float fS = (float)(s0i + j);

        const float mu = fmaf(M0, re, fmaf(M1, im, fmaf(M2, fS, M3)));
        const float ms = fmaf(re, fmaf(E00, re, fmaf(F01, im, fmaf(F02, fS, F03))),
                         fmaf(im, fmaf(E11, im, fmaf(F12, fS, F13)),
                         fmaf(fS, fmaf(E22, fS, F23), E33)));
        const float var  = fmaf(-mu, mu, ms);
        const float rstd = rsqrtf(var + LN_EPS);

        f4 o;
#pragma unroll
        for (int k = 0; k < 4; ++k) {
            const float t = fmaf(re, a0[k], fmaf(im, a1[k], fmaf(fS, a2[k], wv[k])));
            o[k] = fmaf((t - mu) * rstd, gv[k], bv[k]);
        }
        __builtin_nontemporal_store(o, (f4*)(op + (size_t)j * D_MODEL));
    }
}

extern "C" void kernel_launch(void* const* d_in, const int* in_sizes, int n_in,
                              void* d_out, int out_size, void* d_ws, size_t ws_size,
                              hipStream_t stream) {
    const float* csi_real = (const float*)d_in[0];
    const float* csi_imag = (const float*)d_in[1];
    const float* w_c      = (const float*)d_in[2];
    const float* b_c      = (const float*)d_in[3];
    const float* w_s      = (const float*)d_in[4];
    const float* b_s      = (const float*)d_in[5];
    const float* w_u      = (const float*)d_in[6];
    const float* b_u      = (const float*)d_in[7];
    const float* w_f      = (const float*)d_in[8];
    const float* b_f      = (const float*)d_in[9];
    const float* ln_gamma = (const float*)d_in[10];
    const float* ln_beta  = (const float*)d_in[11];
    float* out = (float*)d_out;

    // 2048 blocks x 4 waves = 8192 waves; each owns a contiguous 64-row chunk.
    csi_encoder_kernel<<<2048, 256, 0, stream>>>(
        csi_real, csi_imag, w_c, b_c, w_s, b_s, w_u, b_u, w_f, b_f,
        ln_gamma, ln_beta, out);
}